// Round 2
// baseline (824.229 us; speedup 1.0000x reference)
//
#include <hip/hip_runtime.h>

// ================= problem constants =================
#define NB       524288
#define OBSD     42
#define HD       128
#define NROWS    64           // rows per block
#define NTHREADS 512          // 8 waves
#define NBLOCKS  (NB / NROWS) // 8192

// ws packed-weight offsets (ushort elements), each matrix as [K/32][128][32] bf16
#define WS_SELF  0
#define WS_ENEMY 4096
#define WS_ALLY  8192
#define WS_EMAT  12288
#define WS_AMAT  28672
#define WS_ENC1  45056
#define WS_ENC2  94208
#define WS_TOTAL 110592

// LDS layout (ushort elements); strides padded +8 -> <=2-way bank conflicts
#define L_SELFA  0        // [64][40]  bf16, K-padded self inputs (17 -> 32)
#define L_ENA    2560     // [192][40] bf16, enemy entity inputs (5 -> 32)
#define L_ALA    10240    // [128][40] bf16, ally entity inputs  (5 -> 32)
#define L_ABUF   15360    // size of staging region (aliased by h1 later)
#define L_H      15360    // [64][392] bf16: cols 0-127 self_emb |128-255 e_att |256-383 a_att
#define L_EEMB   40448    // [192][136] bf16 enemy embeddings; later aliased by ally [128][136]
#define L_Q      66560    // [64][136] bf16: e_q, later a_q
#define L_H1     0        // alias over staging: [64][136] bf16
#define L_TOTAL  75264    // ushorts -> 150528 bytes LDS

typedef __attribute__((ext_vector_type(8))) __bf16 bf16x8;
typedef __attribute__((ext_vector_type(4))) float f32x4;
typedef __attribute__((ext_vector_type(8))) unsigned short u16x8;
typedef __attribute__((ext_vector_type(4))) unsigned int u32x4;
typedef unsigned short ushort_t;
typedef unsigned int uint_t;

#define MFMA16(a,b,c) __builtin_amdgcn_mfma_f32_16x16x32_bf16((a),(b),(c),0,0,0)

__device__ __forceinline__ ushort_t f2bf(float v){            // RNE f32->bf16
  uint_t u = __float_as_uint(v);
  return (ushort_t)((u + 0x7FFFu + ((u >> 16) & 1u)) >> 16);
}
__device__ __forceinline__ float bf2f(ushort_t b){
  return __uint_as_float(((uint_t)b) << 16);
}
__device__ __forceinline__ float fast_tanh(float x){
  // tanh(x) = 1 - 2/(exp2(2*log2e*x)+1); exact at +-inf, ~1ulp transcendentals
  float e = __builtin_amdgcn_exp2f(x * 2.8853900817779268f);
  return 1.0f - 2.0f * __builtin_amdgcn_rcpf(e + 1.0f);
}

// ---- repack: fp32 weights -> bf16 [K/32][128][32], zero-padded in K ----
__global__ void repack_kernel(const float* __restrict__ selfW,
                              const float* __restrict__ enemyW,
                              const float* __restrict__ allyW,
                              const float* __restrict__ emat,
                              const float* __restrict__ amat,
                              const float* __restrict__ enc1,
                              const float* __restrict__ enc2,
                              ushort_t* __restrict__ ws)
{
  int g = blockIdx.x * 256 + threadIdx.x;   // exactly 110592 threads
  int ktg = g >> 12;                        // global ktile (4096 elems each)
  int within = g & 4095;
  int n  = within >> 5;
  int ki = within & 31;
  const float* src; int K; int kt;
  if      (ktg < 1) { src = selfW;  K = 17;  kt = ktg;      }
  else if (ktg < 2) { src = enemyW; K = 5;   kt = ktg - 1;  }
  else if (ktg < 3) { src = allyW;  K = 5;   kt = ktg - 2;  }
  else if (ktg < 7) { src = emat;   K = 128; kt = ktg - 3;  }
  else if (ktg < 11){ src = amat;   K = 128; kt = ktg - 7;  }
  else if (ktg < 23){ src = enc1;   K = 384; kt = ktg - 11; }
  else              { src = enc2;   K = 128; kt = ktg - 23; }
  int k = kt * 32 + ki;
  float v = (k < K) ? src[k * HD + n] : 0.0f;
  ws[g] = f2bf(v);   // dst offset == prefix(ktiles)*4096 + local, matches WS_* table
}

// ================= main fused kernel =================
__global__ __launch_bounds__(NTHREADS, 2)
void obs_encoder_kernel(const float* __restrict__ inp,
                        const float* __restrict__ self_b,
                        const float* __restrict__ enemy_b,
                        const float* __restrict__ ally_b,
                        const float* __restrict__ enc1_b,
                        const float* __restrict__ enc2_b,
                        const ushort_t* __restrict__ ws,
                        float* __restrict__ out)
{
  extern __shared__ __align__(16) ushort_t lds[];
  const int tid = threadIdx.x;
  const int bid = blockIdx.x;
  const int l  = tid & 63;
  const int w  = tid >> 6;     // wave 0..7
  const int lc = l & 15;       // MFMA: A-row / B-col / C-col lane index
  const int lg = l >> 4;       // MFMA: k-group (A/B) / row-group (C)
  const int rh = w >> 2;       // row-half (0/1): row-tiles [rh*RT/2, ...)
  const int cp = w & 3;        // col-pair: cols cp*32 .. cp*32+31
  const int c0 = cp * 32;

  // ---- phase 0: zero A-staging (K-pad regions must be 0) ----
  {
    u32x4 zz = 0;
    for (int i = tid; i < L_ABUF / 8; i += NTHREADS)
      *(u32x4*)&lds[i * 8] = zz;
  }
  __syncthreads();

  // ---- phase 1: load 64x42 input rows (fully coalesced), route to A-tiles ----
  {
    const int inbase = bid * (NROWS * OBSD);
    for (int i = tid; i < NROWS * OBSD; i += NTHREADS){
      ushort_t bv = f2bf(inp[inbase + i]);
      int row = i / OBSD, col = i - row * OBSD;
      int dst;
      if (col < 4)        dst = L_SELFA + row * 40 + col;                       // move
      else if (col < 19)  { int c = col - 4;  dst = L_ENA + (row * 3 + c / 5) * 40 + c % 5; }
      else if (col < 29)  { int c = col - 19; dst = L_ALA + (row * 2 + c / 5) * 40 + c % 5; }
      else if (col == 29) dst = L_SELFA + row * 40 + 4;                         // own
      else                dst = L_SELFA + row * 40 + 5 + (col - 30);            // last12
      lds[dst] = bv;
    }
  }
  __syncthreads();

  // ---- phase 2: self_emb -> h[:,0:128]; enemy_emb -> eEmb ----
  {
    bf16x8 b0 = *(const bf16x8*)&ws[WS_SELF + (c0 + lc) * 32 + lg * 8];
    bf16x8 b1 = *(const bf16x8*)&ws[WS_SELF + (c0 + 16 + lc) * 32 + lg * 8];
    float bias0 = self_b[c0 + lc], bias1 = self_b[c0 + 16 + lc];
    #pragma unroll
    for (int rr = 0; rr < 2; ++rr){
      int rt = rh * 2 + rr;
      bf16x8 a = *(const bf16x8*)&lds[L_SELFA + (rt * 16 + lc) * 40 + lg * 8];
      f32x4 z = {0.f,0.f,0.f,0.f};
      f32x4 acc0 = MFMA16(a, b0, z);
      f32x4 acc1 = MFMA16(a, b1, z);
      #pragma unroll
      for (int j = 0; j < 4; ++j){
        int row = rt * 16 + lg * 4 + j;
        lds[L_H + row * 392 + c0 + lc]      = f2bf(fast_tanh(acc0[j] + bias0));
        lds[L_H + row * 392 + c0 + 16 + lc] = f2bf(fast_tanh(acc1[j] + bias1));
      }
    }
    bf16x8 e0 = *(const bf16x8*)&ws[WS_ENEMY + (c0 + lc) * 32 + lg * 8];
    bf16x8 e1 = *(const bf16x8*)&ws[WS_ENEMY + (c0 + 16 + lc) * 32 + lg * 8];
    float biasE0 = enemy_b[c0 + lc], biasE1 = enemy_b[c0 + 16 + lc];
    #pragma unroll
    for (int rr = 0; rr < 6; ++rr){        // 192 entity rows = 12 tiles, half per wave
      int rt = rh * 6 + rr;
      bf16x8 a = *(const bf16x8*)&lds[L_ENA + (rt * 16 + lc) * 40 + lg * 8];
      f32x4 z = {0.f,0.f,0.f,0.f};
      f32x4 acc0 = MFMA16(a, e0, z);
      f32x4 acc1 = MFMA16(a, e1, z);
      #pragma unroll
      for (int j = 0; j < 4; ++j){
        int ent = rt * 16 + lg * 4 + j;
        lds[L_EEMB + ent * 136 + c0 + lc]      = f2bf(fast_tanh(acc0[j] + biasE0));
        lds[L_EEMB + ent * 136 + c0 + 16 + lc] = f2bf(fast_tanh(acc1[j] + biasE1));
      }
    }
  }
  __syncthreads();

  // ---- phase 3: e_q = self_emb @ enemy_mat -> qBuf (bf16, no bias/tanh) ----
  {
    f32x4 acc[2][2] = {{{0.f,0.f,0.f,0.f},{0.f,0.f,0.f,0.f}},
                       {{0.f,0.f,0.f,0.f},{0.f,0.f,0.f,0.f}}};
    #pragma unroll
    for (int ks = 0; ks < 4; ++ks){
      bf16x8 b0 = *(const bf16x8*)&ws[WS_EMAT + (ks * HD + c0 + lc) * 32 + lg * 8];
      bf16x8 b1 = *(const bf16x8*)&ws[WS_EMAT + (ks * HD + c0 + 16 + lc) * 32 + lg * 8];
      #pragma unroll
      for (int rr = 0; rr < 2; ++rr){
        int rt = rh * 2 + rr;
        bf16x8 a = *(const bf16x8*)&lds[L_H + (rt * 16 + lc) * 392 + ks * 32 + lg * 8];
        acc[rr][0] = MFMA16(a, b0, acc[rr][0]);
        acc[rr][1] = MFMA16(a, b1, acc[rr][1]);
      }
    }
    #pragma unroll
    for (int rr = 0; rr < 2; ++rr)
      #pragma unroll
      for (int j = 0; j < 4; ++j){
        int row = (rh * 2 + rr) * 16 + lg * 4 + j;
        lds[L_Q + row * 136 + c0 + lc]      = f2bf(acc[rr][0][j]);
        lds[L_Q + row * 136 + c0 + 16 + lc] = f2bf(acc[rr][1][j]);
      }
  }
  __syncthreads();

  // ---- phase 4: enemy attention (VALU): 8 lanes per row ----
  {
    int r  = tid >> 3;
    int cb = (tid & 7) * 16;
    float q[16], em[3][16], dot[3];
    u16x8 q0 = *(const u16x8*)&lds[L_Q + r * 136 + cb];
    u16x8 q1 = *(const u16x8*)&lds[L_Q + r * 136 + cb + 8];
    #pragma unroll
    for (int j = 0; j < 8; ++j){ q[j] = bf2f(q0[j]); q[j + 8] = bf2f(q1[j]); }
    #pragma unroll
    for (int n = 0; n < 3; ++n){
      u16x8 s0 = *(const u16x8*)&lds[L_EEMB + (r * 3 + n) * 136 + cb];
      u16x8 s1 = *(const u16x8*)&lds[L_EEMB + (r * 3 + n) * 136 + cb + 8];
      float s = 0.f;
      #pragma unroll
      for (int j = 0; j < 8; ++j){ em[n][j] = bf2f(s0[j]); em[n][j + 8] = bf2f(s1[j]); }
      #pragma unroll
      for (int j = 0; j < 16; ++j) s += q[j] * em[n][j];
      dot[n] = s;
    }
    #pragma unroll
    for (int n = 0; n < 3; ++n){
      dot[n] += __shfl_xor(dot[n], 1);
      dot[n] += __shfl_xor(dot[n], 2);
      dot[n] += __shfl_xor(dot[n], 4);
    }
    const float SC = 0.08838834764831845f * 1.4426950408889634f; // scale * log2e
    float s0 = dot[0] * SC, s1 = dot[1] * SC, s2 = dot[2] * SC;
    float m = fmaxf(fmaxf(s0, s1), s2);
    float x0 = __builtin_amdgcn_exp2f(s0 - m);
    float x1 = __builtin_amdgcn_exp2f(s1 - m);
    float x2 = __builtin_amdgcn_exp2f(s2 - m);
    float rs = __builtin_amdgcn_rcpf(x0 + x1 + x2);
    float a0 = x0 * rs, a1 = x1 * rs, a2 = x2 * rs;
    u16x8 o0, o1;
    #pragma unroll
    for (int j = 0; j < 8; ++j){
      o0[j] = f2bf(a0 * em[0][j]     + a1 * em[1][j]     + a2 * em[2][j]);
      o1[j] = f2bf(a0 * em[0][j + 8] + a1 * em[1][j + 8] + a2 * em[2][j + 8]);
    }
    *(u16x8*)&lds[L_H + r * 392 + 128 + cb]     = o0;
    *(u16x8*)&lds[L_H + r * 392 + 128 + cb + 8] = o1;
  }
  __syncthreads();

  // ---- phase 5: ally_emb -> (aliased) eEmb region; a_q -> qBuf ----
  {
    bf16x8 b0 = *(const bf16x8*)&ws[WS_ALLY + (c0 + lc) * 32 + lg * 8];
    bf16x8 b1 = *(const bf16x8*)&ws[WS_ALLY + (c0 + 16 + lc) * 32 + lg * 8];
    float biasA0 = ally_b[c0 + lc], biasA1 = ally_b[c0 + 16 + lc];
    #pragma unroll
    for (int rr = 0; rr < 4; ++rr){        // 128 entity rows = 8 tiles
      int rt = rh * 4 + rr;
      bf16x8 a = *(const bf16x8*)&lds[L_ALA + (rt * 16 + lc) * 40 + lg * 8];
      f32x4 z = {0.f,0.f,0.f,0.f};
      f32x4 acc0 = MFMA16(a, b0, z);
      f32x4 acc1 = MFMA16(a, b1, z);
      #pragma unroll
      for (int j = 0; j < 4; ++j){
        int ent = rt * 16 + lg * 4 + j;
        lds[L_EEMB + ent * 136 + c0 + lc]      = f2bf(fast_tanh(acc0[j] + biasA0));
        lds[L_EEMB + ent * 136 + c0 + 16 + lc] = f2bf(fast_tanh(acc1[j] + biasA1));
      }
    }
    f32x4 acc[2][2] = {{{0.f,0.f,0.f,0.f},{0.f,0.f,0.f,0.f}},
                       {{0.f,0.f,0.f,0.f},{0.f,0.f,0.f,0.f}}};
    #pragma unroll
    for (int ks = 0; ks < 4; ++ks){
      bf16x8 w0 = *(const bf16x8*)&ws[WS_AMAT + (ks * HD + c0 + lc) * 32 + lg * 8];
      bf16x8 w1 = *(const bf16x8*)&ws[WS_AMAT + (ks * HD + c0 + 16 + lc) * 32 + lg * 8];
      #pragma unroll
      for (int rr = 0; rr < 2; ++rr){
        int rt = rh * 2 + rr;
        bf16x8 a = *(const bf16x8*)&lds[L_H + (rt * 16 + lc) * 392 + ks * 32 + lg * 8];
        acc[rr][0] = MFMA16(a, w0, acc[rr][0]);
        acc[rr][1] = MFMA16(a, w1, acc[rr][1]);
      }
    }
    #pragma unroll
    for (int rr = 0; rr < 2; ++rr)
      #pragma unroll
      for (int j = 0; j < 4; ++j){
        int row = (rh * 2 + rr) * 16 + lg * 4 + j;
        lds[L_Q + row * 136 + c0 + lc]      = f2bf(acc[rr][0][j]);
        lds[L_Q + row * 136 + c0 + 16 + lc] = f2bf(acc[rr][1][j]);
      }
  }
  __syncthreads();

  // ---- phase 6: ally attention -> h[:,256:384] ----
  {
    int r  = tid >> 3;
    int cb = (tid & 7) * 16;
    float q[16], em[2][16], dot[2];
    u16x8 q0 = *(const u16x8*)&lds[L_Q + r * 136 + cb];
    u16x8 q1 = *(const u16x8*)&lds[L_Q + r * 136 + cb + 8];
    #pragma unroll
    for (int j = 0; j < 8; ++j){ q[j] = bf2f(q0[j]); q[j + 8] = bf2f(q1[j]); }
    #pragma unroll
    for (int n = 0; n < 2; ++n){
      u16x8 s0 = *(const u16x8*)&lds[L_EEMB + (r * 2 + n) * 136 + cb];
      u16x8 s1 = *(const u16x8*)&lds[L_EEMB + (r * 2 + n) * 136 + cb + 8];
      float s = 0.f;
      #pragma unroll
      for (int j = 0; j < 8; ++j){ em[n][j] = bf2f(s0[j]); em[n][j + 8] = bf2f(s1[j]); }
      #pragma unroll
      for (int j = 0; j < 16; ++j) s += q[j] * em[n][j];
      dot[n] = s;
    }
    #pragma unroll
    for (int n = 0; n < 2; ++n){
      dot[n] += __shfl_xor(dot[n], 1);
      dot[n] += __shfl_xor(dot[n], 2);
      dot[n] += __shfl_xor(dot[n], 4);
    }
    const float SC = 0.08838834764831845f * 1.4426950408889634f;
    float s0 = dot[0] * SC, s1 = dot[1] * SC;
    float m = fmaxf(s0, s1);
    float x0 = __builtin_amdgcn_exp2f(s0 - m);
    float x1 = __builtin_amdgcn_exp2f(s1 - m);
    float rs = __builtin_amdgcn_rcpf(x0 + x1);
    float a0 = x0 * rs, a1 = x1 * rs;
    u16x8 o0, o1;
    #pragma unroll
    for (int j = 0; j < 8; ++j){
      o0[j] = f2bf(a0 * em[0][j]     + a1 * em[1][j]);
      o1[j] = f2bf(a0 * em[0][j + 8] + a1 * em[1][j + 8]);
    }
    *(u16x8*)&lds[L_H + r * 392 + 256 + cb]     = o0;
    *(u16x8*)&lds[L_H + r * 392 + 256 + cb + 8] = o1;
  }
  __syncthreads();

  // ---- phase 7: enc1 (K=384) -> h1 (aliases dead A-staging) ----
  {
    f32x4 acc[2][2] = {{{0.f,0.f,0.f,0.f},{0.f,0.f,0.f,0.f}},
                       {{0.f,0.f,0.f,0.f},{0.f,0.f,0.f,0.f}}};
    #pragma unroll
    for (int ks = 0; ks < 12; ++ks){
      bf16x8 b0 = *(const bf16x8*)&ws[WS_ENC1 + (ks * HD + c0 + lc) * 32 + lg * 8];
      bf16x8 b1 = *(const bf16x8*)&ws[WS_ENC1 + (ks * HD + c0 + 16 + lc) * 32 + lg * 8];
      #pragma unroll
      for (int rr = 0; rr < 2; ++rr){
        int rt = rh * 2 + rr;
        bf16x8 a = *(const bf16x8*)&lds[L_H + (rt * 16 + lc) * 392 + ks * 32 + lg * 8];
        acc[rr][0] = MFMA16(a, b0, acc[rr][0]);
        acc[rr][1] = MFMA16(a, b1, acc[rr][1]);
      }
    }
    float b10 = enc1_b[c0 + lc], b11 = enc1_b[c0 + 16 + lc];
    #pragma unroll
    for (int rr = 0; rr < 2; ++rr)
      #pragma unroll
      for (int j = 0; j < 4; ++j){
        int row = (rh * 2 + rr) * 16 + lg * 4 + j;
        lds[L_H1 + row * 136 + c0 + lc]      = f2bf(fast_tanh(acc[rr][0][j] + b10));
        lds[L_H1 + row * 136 + c0 + 16 + lc] = f2bf(fast_tanh(acc[rr][1][j] + b11));
      }
  }
  __syncthreads();

  // ---- phase 8: enc2 (K=128) -> tanh -> global out (fp32) ----
  {
    f32x4 acc[2][2] = {{{0.f,0.f,0.f,0.f},{0.f,0.f,0.f,0.f}},
                       {{0.f,0.f,0.f,0.f},{0.f,0.f,0.f,0.f}}};
    #pragma unroll
    for (int ks = 0; ks < 4; ++ks){
      bf16x8 b0 = *(const bf16x8*)&ws[WS_ENC2 + (ks * HD + c0 + lc) * 32 + lg * 8];
      bf16x8 b1 = *(const bf16x8*)&ws[WS_ENC2 + (ks * HD + c0 + 16 + lc) * 32 + lg * 8];
      #pragma unroll
      for (int rr = 0; rr < 2; ++rr){
        int rt = rh * 2 + rr;
        bf16x8 a = *(const bf16x8*)&lds[L_H1 + (rt * 16 + lc) * 136 + ks * 32 + lg * 8];
        acc[rr][0] = MFMA16(a, b0, acc[rr][0]);
        acc[rr][1] = MFMA16(a, b1, acc[rr][1]);
      }
    }
    float b20 = enc2_b[c0 + lc], b21 = enc2_b[c0 + 16 + lc];
    #pragma unroll
    for (int rr = 0; rr < 2; ++rr)
      #pragma unroll
      for (int j = 0; j < 4; ++j){
        int row = (rh * 2 + rr) * 16 + lg * 4 + j;
        long gi = (long)(bid * NROWS + row) * HD;
        out[gi + c0 + lc]      = fast_tanh(acc[rr][0][j] + b20);
        out[gi + c0 + 16 + lc] = fast_tanh(acc[rr][1][j] + b21);
      }
  }
}

extern "C" void kernel_launch(void* const* d_in, const int* in_sizes, int n_in,
                              void* d_out, int out_size, void* d_ws, size_t ws_size,
                              hipStream_t stream)
{
  const float* inp    = (const float*)d_in[0];
  const float* selfW  = (const float*)d_in[1];
  const float* selfb  = (const float*)d_in[2];
  const float* enemyW = (const float*)d_in[3];
  const float* enemyb = (const float*)d_in[4];
  const float* allyW  = (const float*)d_in[5];
  const float* allyb  = (const float*)d_in[6];
  const float* emat   = (const float*)d_in[7];
  const float* amat   = (const float*)d_in[8];
  const float* enc1W  = (const float*)d_in[9];
  const float* enc1b  = (const float*)d_in[10];
  const float* enc2W  = (const float*)d_in[11];
  const float* enc2b  = (const float*)d_in[12];
  ushort_t* ws  = (ushort_t*)d_ws;
  float*    out = (float*)d_out;

  (void)hipFuncSetAttribute((const void*)obs_encoder_kernel,
                            hipFuncAttributeMaxDynamicSharedMemorySize,
                            L_TOTAL * 2);

  repack_kernel<<<WS_TOTAL / 256, 256, 0, stream>>>(selfW, enemyW, allyW, emat, amat,
                                                    enc1W, enc2W, ws);
  obs_encoder_kernel<<<NBLOCKS, NTHREADS, L_TOTAL * 2, stream>>>(
      inp, selfb, enemyb, allyb, enc1b, enc2b, ws, out);
}

// Round 4
// 780.840 us; speedup vs baseline: 1.0556x; 1.0556x over previous
//
#include <hip/hip_runtime.h>

// ================= problem constants =================
#define NB       524288
#define OBSD     42
#define HD       128
#define NROWS    32           // rows per block
#define NTHREADS 512          // 8 waves
#define NBLOCKS  (NB / NROWS) // 16384

// ws packed-weight offsets (ushort elements), each matrix as [K/32][128][32] bf16
#define WS_SELF  0
#define WS_ENEMY 4096
#define WS_ALLY  8192
#define WS_EMAT  12288
#define WS_AMAT  28672
#define WS_ENC1  45056
#define WS_ENC2  94208
#define WS_TOTAL 110592

// LDS layout (ushort elements). 81408 bytes total -> 2 blocks/CU (162816 <= 163840).
#define L_SELFA  0        // [32][40] bf16, K-padded self inputs (17 -> 32)
#define L_ENA    1280     // [96][40] enemy entity inputs (5 -> 32)
#define L_ALA    5120     // [64][40] ally entity inputs  (5 -> 32)
// staging (0..7679) dead after P2 -> aliased:
#define L_Q      0        // [32][128] bf16: e_q (P3a..P4a), then a_q (P3b..P4b)
#define L_H1     0        // [32][136] bf16 enc1 output (P5..P6)
#define L_H      7680     // [32][392] bf16: 0-127 self_emb | 128-255 e_att | 256-383 a_att
#define L_EE     20224    // [96][128] bf16 enemy embeddings
#define L_AE     32512    // [64][128] bf16 ally embeddings
#define L_TOTAL  40704    // ushorts -> 81408 bytes

typedef __attribute__((ext_vector_type(8))) __bf16 bf16x8;
typedef __attribute__((ext_vector_type(4))) float f32x4;
typedef __attribute__((ext_vector_type(8))) unsigned short u16x8;
typedef __attribute__((ext_vector_type(4))) unsigned int u32x4;
typedef unsigned short ushort_t;
typedef unsigned int uint_t;

#define MFMA16(a,b,c) __builtin_amdgcn_mfma_f32_16x16x32_bf16((a),(b),(c),0,0,0)

// native casts: compiler lowers f32<->bf16 to v_cvt_pk_bf16_f32 / shift (1 op)
__device__ __forceinline__ ushort_t f2bf(float v){
  return __builtin_bit_cast(ushort_t, (__bf16)v);
}
__device__ __forceinline__ float bf2f(ushort_t b){
  return (float)__builtin_bit_cast(__bf16, b);
}
__device__ __forceinline__ float fast_tanh(float x){
  // tanh(x) = 1 - 2/(exp2(2*log2e*x)+1)
  float e = __builtin_amdgcn_exp2f(x * 2.8853900817779268f);
  return __builtin_fmaf(-2.0f, __builtin_amdgcn_rcpf(e + 1.0f), 1.0f);
}

// ---- repack: fp32 weights -> bf16 [K/32][128][32], zero-padded in K ----
__global__ void repack_kernel(const float* __restrict__ selfW,
                              const float* __restrict__ enemyW,
                              const float* __restrict__ allyW,
                              const float* __restrict__ emat,
                              const float* __restrict__ amat,
                              const float* __restrict__ enc1,
                              const float* __restrict__ enc2,
                              ushort_t* __restrict__ ws)
{
  int g = blockIdx.x * 256 + threadIdx.x;   // exactly 110592 threads
  int ktg = g >> 12;
  int within = g & 4095;
  int n  = within >> 5;
  int ki = within & 31;
  const float* src; int K; int kt;
  if      (ktg < 1) { src = selfW;  K = 17;  kt = ktg;      }
  else if (ktg < 2) { src = enemyW; K = 5;   kt = ktg - 1;  }
  else if (ktg < 3) { src = allyW;  K = 5;   kt = ktg - 2;  }
  else if (ktg < 7) { src = emat;   K = 128; kt = ktg - 3;  }
  else if (ktg < 11){ src = amat;   K = 128; kt = ktg - 7;  }
  else if (ktg < 23){ src = enc1;   K = 384; kt = ktg - 11; }
  else              { src = enc2;   K = 128; kt = ktg - 23; }
  int k = kt * 32 + ki;
  float v = (k < K) ? src[k * HD + n] : 0.0f;
  ws[g] = f2bf(v);
}

// ================= main fused kernel =================
__global__ __launch_bounds__(NTHREADS, 4)
void obs_encoder_kernel(const float* __restrict__ inp,
                        const float* __restrict__ self_b,
                        const float* __restrict__ enemy_b,
                        const float* __restrict__ ally_b,
                        const float* __restrict__ enc1_b,
                        const float* __restrict__ enc2_b,
                        const ushort_t* __restrict__ ws,
                        float* __restrict__ out)
{
  extern __shared__ __align__(16) ushort_t lds[];
  const int tid = threadIdx.x;
  const int bid = blockIdx.x;
  const int l  = tid & 63;
  const int w  = tid >> 6;     // wave 0..7
  const int lc = l & 15;       // MFMA: A-row / B-col / C-col lane index
  const int lg = l >> 4;       // MFMA: k-group (A/B) / row-group (C)
  const int rh = w >> 2;       // row-tile (0/1) of 16 rows
  const int cp = w & 3;        // col-pair: cols cp*32 .. cp*32+31
  const int c0 = cp * 32;

  // ---- P0: zero staging (K-pad regions must be 0) ----
  {
    u32x4 zz = 0;
    for (int i = tid; i < 960; i += NTHREADS)     // 7680 ushorts
      *(u32x4*)&lds[i * 8] = zz;
  }
  __syncthreads();

  // ---- P1: load 32x42 input rows, route to A-staging tiles ----
  {
    const int inbase = bid * (NROWS * OBSD);
    for (int i = tid; i < NROWS * OBSD; i += NTHREADS){
      ushort_t bv = f2bf(inp[inbase + i]);
      int row = i / OBSD, col = i - row * OBSD;
      int dst;
      if (col < 4)        dst = L_SELFA + row * 40 + col;
      else if (col < 19)  { int c = col - 4;  dst = L_ENA + (row * 3 + c / 5) * 40 + c % 5; }
      else if (col < 29)  { int c = col - 19; dst = L_ALA + (row * 2 + c / 5) * 40 + c % 5; }
      else if (col == 29) dst = L_SELFA + row * 40 + 4;
      else                dst = L_SELFA + row * 40 + 5 + (col - 30);
      lds[dst] = bv;
    }
  }
  __syncthreads();

  // ---- P2: all embeddings: self -> H[:,0:128], enemy -> EE, ally -> AE ----
  {
    // self (1 row-tile per wave)
    {
      bf16x8 b0 = *(const bf16x8*)&ws[WS_SELF + (c0 + lc) * 32 + lg * 8];
      bf16x8 b1 = *(const bf16x8*)&ws[WS_SELF + (c0 + 16 + lc) * 32 + lg * 8];
      float bias0 = self_b[c0 + lc], bias1 = self_b[c0 + 16 + lc];
      bf16x8 a = *(const bf16x8*)&lds[L_SELFA + (rh * 16 + lc) * 40 + lg * 8];
      f32x4 z = {0.f,0.f,0.f,0.f};
      f32x4 acc0 = MFMA16(a, b0, z);
      f32x4 acc1 = MFMA16(a, b1, z);
      #pragma unroll
      for (int j = 0; j < 4; ++j){
        int row = rh * 16 + lg * 4 + j;
        lds[L_H + row * 392 + c0 + lc]      = f2bf(fast_tanh(acc0[j] + bias0));
        lds[L_H + row * 392 + c0 + 16 + lc] = f2bf(fast_tanh(acc1[j] + bias1));
      }
    }
    // enemy (3 tiles per wave: 96 entity rows total)
    {
      bf16x8 e0 = *(const bf16x8*)&ws[WS_ENEMY + (c0 + lc) * 32 + lg * 8];
      bf16x8 e1 = *(const bf16x8*)&ws[WS_ENEMY + (c0 + 16 + lc) * 32 + lg * 8];
      float biasE0 = enemy_b[c0 + lc], biasE1 = enemy_b[c0 + 16 + lc];
      #pragma unroll
      for (int rr = 0; rr < 3; ++rr){
        int rt = rh * 3 + rr;
        bf16x8 a = *(const bf16x8*)&lds[L_ENA + (rt * 16 + lc) * 40 + lg * 8];
        f32x4 z = {0.f,0.f,0.f,0.f};
        f32x4 acc0 = MFMA16(a, e0, z);
        f32x4 acc1 = MFMA16(a, e1, z);
        #pragma unroll
        for (int j = 0; j < 4; ++j){
          int ent = rt * 16 + lg * 4 + j;
          lds[L_EE + ent * 128 + c0 + lc]      = f2bf(fast_tanh(acc0[j] + biasE0));
          lds[L_EE + ent * 128 + c0 + 16 + lc] = f2bf(fast_tanh(acc1[j] + biasE1));
        }
      }
    }
    // ally (2 tiles per wave: 64 entity rows total)
    {
      bf16x8 a0w = *(const bf16x8*)&ws[WS_ALLY + (c0 + lc) * 32 + lg * 8];
      bf16x8 a1w = *(const bf16x8*)&ws[WS_ALLY + (c0 + 16 + lc) * 32 + lg * 8];
      float biasA0 = ally_b[c0 + lc], biasA1 = ally_b[c0 + 16 + lc];
      #pragma unroll
      for (int rr = 0; rr < 2; ++rr){
        int rt = rh * 2 + rr;
        bf16x8 a = *(const bf16x8*)&lds[L_ALA + (rt * 16 + lc) * 40 + lg * 8];
        f32x4 z = {0.f,0.f,0.f,0.f};
        f32x4 acc0 = MFMA16(a, a0w, z);
        f32x4 acc1 = MFMA16(a, a1w, z);
        #pragma unroll
        for (int j = 0; j < 4; ++j){
          int ent = rt * 16 + lg * 4 + j;
          lds[L_AE + ent * 128 + c0 + lc]      = f2bf(fast_tanh(acc0[j] + biasA0));
          lds[L_AE + ent * 128 + c0 + 16 + lc] = f2bf(fast_tanh(acc1[j] + biasA1));
        }
      }
    }
  }
  __syncthreads();

  // ---- P3a: e_q = self_emb @ enemy_mat -> Q (bf16, no bias/tanh) ----
  {
    f32x4 acc0 = {0.f,0.f,0.f,0.f}, acc1 = {0.f,0.f,0.f,0.f};
    #pragma unroll
    for (int ks = 0; ks < 4; ++ks){
      bf16x8 b0 = *(const bf16x8*)&ws[WS_EMAT + (ks * HD + c0 + lc) * 32 + lg * 8];
      bf16x8 b1 = *(const bf16x8*)&ws[WS_EMAT + (ks * HD + c0 + 16 + lc) * 32 + lg * 8];
      bf16x8 a = *(const bf16x8*)&lds[L_H + (rh * 16 + lc) * 392 + ks * 32 + lg * 8];
      acc0 = MFMA16(a, b0, acc0);
      acc1 = MFMA16(a, b1, acc1);
    }
    #pragma unroll
    for (int j = 0; j < 4; ++j){
      int row = rh * 16 + lg * 4 + j;
      lds[L_Q + row * 128 + c0 + lc]      = f2bf(acc0[j]);
      lds[L_Q + row * 128 + c0 + 16 + lc] = f2bf(acc1[j]);
    }
  }
  __syncthreads();

  // ---- P4a: enemy attention (16 lanes/row, 8 cols each) -> H[:,128:256] ----
  {
    int r  = tid >> 4;
    int cb = (tid & 15) * 8;
    float q[8], em[3][8], dot[3];
    u16x8 qv = *(const u16x8*)&lds[L_Q + r * 128 + cb];
    #pragma unroll
    for (int j = 0; j < 8; ++j) q[j] = bf2f(qv[j]);
    #pragma unroll
    for (int n = 0; n < 3; ++n){
      u16x8 ev = *(const u16x8*)&lds[L_EE + (r * 3 + n) * 128 + cb];
      float s = 0.f;
      #pragma unroll
      for (int j = 0; j < 8; ++j){ em[n][j] = bf2f(ev[j]); s += q[j] * em[n][j]; }
      dot[n] = s;
    }
    #pragma unroll
    for (int n = 0; n < 3; ++n){
      dot[n] += __shfl_xor(dot[n], 1);
      dot[n] += __shfl_xor(dot[n], 2);
      dot[n] += __shfl_xor(dot[n], 4);
      dot[n] += __shfl_xor(dot[n], 8);
    }
    const float SC = 0.08838834764831845f * 1.4426950408889634f; // scale * log2e
    float s0 = dot[0] * SC, s1 = dot[1] * SC, s2 = dot[2] * SC;
    float m = fmaxf(fmaxf(s0, s1), s2);
    float x0 = __builtin_amdgcn_exp2f(s0 - m);
    float x1 = __builtin_amdgcn_exp2f(s1 - m);
    float x2 = __builtin_amdgcn_exp2f(s2 - m);
    float rs = __builtin_amdgcn_rcpf(x0 + x1 + x2);
    float a0 = x0 * rs, a1 = x1 * rs, a2 = x2 * rs;
    u16x8 o;
    #pragma unroll
    for (int j = 0; j < 8; ++j)
      o[j] = f2bf(a0 * em[0][j] + a1 * em[1][j] + a2 * em[2][j]);
    *(u16x8*)&lds[L_H + r * 392 + 128 + cb] = o;
  }
  __syncthreads();

  // ---- P3b: a_q = self_emb @ ally_mat -> Q ----
  {
    f32x4 acc0 = {0.f,0.f,0.f,0.f}, acc1 = {0.f,0.f,0.f,0.f};
    #pragma unroll
    for (int ks = 0; ks < 4; ++ks){
      bf16x8 b0 = *(const bf16x8*)&ws[WS_AMAT + (ks * HD + c0 + lc) * 32 + lg * 8];
      bf16x8 b1 = *(const bf16x8*)&ws[WS_AMAT + (ks * HD + c0 + 16 + lc) * 32 + lg * 8];
      bf16x8 a = *(const bf16x8*)&lds[L_H + (rh * 16 + lc) * 392 + ks * 32 + lg * 8];
      acc0 = MFMA16(a, b0, acc0);
      acc1 = MFMA16(a, b1, acc1);
    }
    #pragma unroll
    for (int j = 0; j < 4; ++j){
      int row = rh * 16 + lg * 4 + j;
      lds[L_Q + row * 128 + c0 + lc]      = f2bf(acc0[j]);
      lds[L_Q + row * 128 + c0 + 16 + lc] = f2bf(acc1[j]);
    }
  }
  __syncthreads();

  // ---- P4b: ally attention -> H[:,256:384] ----
  {
    int r  = tid >> 4;
    int cb = (tid & 15) * 8;
    float q[8], em[2][8], dot[2];
    u16x8 qv = *(const u16x8*)&lds[L_Q + r * 128 + cb];
    #pragma unroll
    for (int j = 0; j < 8; ++j) q[j] = bf2f(qv[j]);
    #pragma unroll
    for (int n = 0; n < 2; ++n){
      u16x8 ev = *(const u16x8*)&lds[L_AE + (r * 2 + n) * 128 + cb];
      float s = 0.f;
      #pragma unroll
      for (int j = 0; j < 8; ++j){ em[n][j] = bf2f(ev[j]); s += q[j] * em[n][j]; }
      dot[n] = s;
    }
    #pragma unroll
    for (int n = 0; n < 2; ++n){
      dot[n] += __shfl_xor(dot[n], 1);
      dot[n] += __shfl_xor(dot[n], 2);
      dot[n] += __shfl_xor(dot[n], 4);
      dot[n] += __shfl_xor(dot[n], 8);
    }
    const float SC = 0.08838834764831845f * 1.4426950408889634f;
    float s0 = dot[0] * SC, s1 = dot[1] * SC;
    float m = fmaxf(s0, s1);
    float x0 = __builtin_amdgcn_exp2f(s0 - m);
    float x1 = __builtin_amdgcn_exp2f(s1 - m);
    float rs = __builtin_amdgcn_rcpf(x0 + x1);
    float a0 = x0 * rs, a1 = x1 * rs;
    u16x8 o;
    #pragma unroll
    for (int j = 0; j < 8; ++j)
      o[j] = f2bf(a0 * em[0][j] + a1 * em[1][j]);
    *(u16x8*)&lds[L_H + r * 392 + 256 + cb] = o;
  }
  __syncthreads();

  // ---- P5: enc1 (K=384) -> H1 (aliases dead staging/Q) ----
  {
    f32x4 acc0 = {0.f,0.f,0.f,0.f}, acc1 = {0.f,0.f,0.f,0.f};
    #pragma unroll
    for (int ks = 0; ks < 12; ++ks){
      bf16x8 b0 = *(const bf16x8*)&ws[WS_ENC1 + (ks * HD + c0 + lc) * 32 + lg * 8];
      bf16x8 b1 = *(const bf16x8*)&ws[WS_ENC1 + (ks * HD + c0 + 16 + lc) * 32 + lg * 8];
      bf16x8 a = *(const bf16x8*)&lds[L_H + (rh * 16 + lc) * 392 + ks * 32 + lg * 8];
      acc0 = MFMA16(a, b0, acc0);
      acc1 = MFMA16(a, b1, acc1);
    }
    float b10 = enc1_b[c0 + lc], b11 = enc1_b[c0 + 16 + lc];
    #pragma unroll
    for (int j = 0; j < 4; ++j){
      int row = rh * 16 + lg * 4 + j;
      lds[L_H1 + row * 136 + c0 + lc]      = f2bf(fast_tanh(acc0[j] + b10));
      lds[L_H1 + row * 136 + c0 + 16 + lc] = f2bf(fast_tanh(acc1[j] + b11));
    }
  }
  __syncthreads();

  // ---- P6: enc2 (K=128) -> tanh -> global out (fp32) ----
  {
    f32x4 acc0 = {0.f,0.f,0.f,0.f}, acc1 = {0.f,0.f,0.f,0.f};
    #pragma unroll
    for (int ks = 0; ks < 4; ++ks){
      bf16x8 b0 = *(const bf16x8*)&ws[WS_ENC2 + (ks * HD + c0 + lc) * 32 + lg * 8];
      bf16x8 b1 = *(const bf16x8*)&ws[WS_ENC2 + (ks * HD + c0 + 16 + lc) * 32 + lg * 8];
      bf16x8 a = *(const bf16x8*)&lds[L_H1 + (rh * 16 + lc) * 136 + ks * 32 + lg * 8];
      acc0 = MFMA16(a, b0, acc0);
      acc1 = MFMA16(a, b1, acc1);
    }
    float b20 = enc2_b[c0 + lc], b21 = enc2_b[c0 + 16 + lc];
    #pragma unroll
    for (int j = 0; j < 4; ++j){
      int row = rh * 16 + lg * 4 + j;
      long gi = (long)(bid * NROWS + row) * HD;
      out[gi + c0 + lc]      = fast_tanh(acc0[j] + b20);
      out[gi + c0 + 16 + lc] = fast_tanh(acc1[j] + b21);
    }
  }
}

extern "C" void kernel_launch(void* const* d_in, const int* in_sizes, int n_in,
                              void* d_out, int out_size, void* d_ws, size_t ws_size,
                              hipStream_t stream)
{
  const float* inp    = (const float*)d_in[0];
  const float* selfW  = (const float*)d_in[1];
  const float* selfb  = (const float*)d_in[2];
  const float* enemyW = (const float*)d_in[3];
  const float* enemyb = (const float*)d_in[4];
  const float* allyW  = (const float*)d_in[5];
  const float* allyb  = (const float*)d_in[6];
  const float* emat   = (const float*)d_in[7];
  const float* amat   = (const float*)d_in[8];
  const float* enc1W  = (const float*)d_in[9];
  const float* enc1b  = (const float*)d_in[10];
  const float* enc2W  = (const float*)d_in[11];
  const float* enc2b  = (const float*)d_in[12];
  ushort_t* ws  = (ushort_t*)d_ws;
  float*    out = (float*)d_out;

  (void)hipFuncSetAttribute((const void*)obs_encoder_kernel,
                            hipFuncAttributeMaxDynamicSharedMemorySize,
                            L_TOTAL * 2);

  repack_kernel<<<WS_TOTAL / 256, 256, 0, stream>>>(selfW, enemyW, allyW, emat, amat,
                                                    enc1W, enc2W, ws);
  obs_encoder_kernel<<<NBLOCKS, NTHREADS, L_TOTAL * 2, stream>>>(
      inp, selfb, enemyb, allyb, enc1b, enc2b, ws, out);
}